// Round 5
// baseline (223.939 us; speedup 1.0000x reference)
//
#include <hip/hip_runtime.h>
#include <hip/hip_bf16.h>
#include <math.h>

#define B_ 4
#define F_ 256
#define C_ 19
#define S_ 256
#define N_ 16384
#define M_ 9728
#define MT_ 38           // m-tiles (256 cols each) in pass1
#define PREP_PRED 256
#define PREP_BUCKET0 2688   // 256 + 2432
#define GEMM_BLKS 512    // 128 panels(128 rows) * 4 mt-chunks, 2 blocks/CU
#define P2_BLOCKS (C_ * 16)

typedef __bf16 bf16_t;
typedef bf16_t bf16x8 __attribute__((ext_vector_type(8)));
typedef float floatx4 __attribute__((ext_vector_type(4)));

#define AS1 __attribute__((address_space(1)))
#define AS3 __attribute__((address_space(3)))

// Fragment-order layout: element (row, f) lives at
//   ((row>>4)*8 + (f>>5))*512 + ((f>>3)&3)*128 + (row&15)*8 + (f&7)
__device__ inline size_t fragoff(int row, int f) {
    return ((size_t)((row >> 4) * 8 + (f >> 5))) * 512
         + (size_t)((((f >> 3) & 3) * 128) + ((row & 15) * 8) + (f & 7));
}

// ---------------- kernel 1: prep (convert + normalize) + bucketing ----------
// ctrl (ccnt/class_sum/done) zeroed by hipMemsetAsync before this kernel.
__global__ __launch_bounds__(256) void k_prep(const float* __restrict__ pred,
                                              const float* __restrict__ mem,
                                              __hip_bfloat16* __restrict__ A16f,
                                              __hip_bfloat16* __restrict__ B16,
                                              const int* __restrict__ labels,
                                              const int* __restrict__ mask,
                                              int* __restrict__ ccnt,
                                              int* __restrict__ pix) {
    int bid = blockIdx.x;
    int t = threadIdx.x;
    if (bid < PREP_PRED) {
        __shared__ float part[4][64];
        __shared__ float invf_s[64];
        int b = bid >> 6, hw0 = (bid & 63) * 64;
        int j = t & 63, q = t >> 6;
        int n0 = b * 4096 + hw0;

        const float* base = pred + ((size_t)b * F_ + q * 64) * 4096 + hw0 + j;
        float v[64];
        float s = 0.f;
        #pragma unroll
        for (int i = 0; i < 64; ++i) {
            float x = base[(size_t)i * 4096];
            v[i] = x;
            s += x * x;
        }
        part[q][j] = s;
        __syncthreads();
        if (t < 64) invf_s[t] = 1.0f / sqrtf(part[0][t] + part[1][t] + part[2][t] + part[3][t]);
        __syncthreads();
        float invf = invf_s[j];
        #pragma unroll
        for (int c = 0; c < 8; ++c) {
            int f = q * 64 + c * 8;
            __hip_bfloat16 tmp[8];
            #pragma unroll
            for (int u = 0; u < 8; ++u) tmp[u] = __float2bfloat16(v[c * 8 + u] * invf);
            *(float4*)&A16f[fragoff(n0 + j, f)] = *(float4*)tmp;
        }
    } else if (bid < PREP_BUCKET0) {
        int row  = (bid - PREP_PRED) * 4 + (t >> 6);
        int lane = t & 63;
        float4 a = ((const float4*)(mem + (size_t)row * F_))[lane];
        float s = a.x*a.x + a.y*a.y + a.z*a.z + a.w*a.w;
        #pragma unroll
        for (int off = 32; off; off >>= 1) s += __shfl_xor(s, off, 64);
        float invm = 1.0f / sqrtf(s);
        __hip_bfloat16 tmp[4];
        tmp[0] = __float2bfloat16(a.x * invm);
        tmp[1] = __float2bfloat16(a.y * invm);
        tmp[2] = __float2bfloat16(a.z * invm);
        tmp[3] = __float2bfloat16(a.w * invm);
        *(float2*)&B16[fragoff(row, lane * 4)] = *(float2*)tmp;
    } else {                                   // ---- bucketing, 256 px/block
        __shared__ int hist[C_], base_s[C_], cur[C_];
        int n0 = (bid - PREP_BUCKET0) * 256;
        if (t < C_) { hist[t] = 0; cur[t] = 0; }
        __syncthreads();
        int myc = labels[n0 + t];
        int mym = mask[n0 + t];
        if (mym) atomicAdd(&hist[myc], 1);
        __syncthreads();
        if (t < C_) base_s[t] = atomicAdd(&ccnt[t], hist[t]);
        __syncthreads();
        if (mym) {
            int o = atomicAdd(&cur[myc], 1);
            pix[myc * N_ + base_s[myc] + o] = n0 + t;
        }
    }
}

// ---------------- kernel 2: pass-1 GEMM, fat wave tiles (128n x 64m) ----------
// 512 blocks = 128 panels * 4 mt-chunks; 256 threads (4 waves); 68 KB LDS
// -> 2 blocks/CU. Each wave owns 128n x 64m: acc[8][4] (128 acc regs),
// 32 MFMA per kt from 8 ds_read + 4 global loads. B traffic halved vs the
// nh-split layout (no duplicate B reads). ILP-regime: long MFMA runs hide
// B L2 latency with only 2 waves/SIMD.
__global__ __launch_bounds__(256, 2) void k_pass1(const __hip_bfloat16* __restrict__ A16f,
                                                  const __hip_bfloat16* __restrict__ B16,
                                                  float* __restrict__ totpart) {
    __shared__ __hip_bfloat16 As[128 * 256];     // 64 KB
    __shared__ float totals_s[2][4][128];        // 4 KB (double-buffered)
    int bid = blockIdx.x;
    int t = threadIdx.x;
    int w = t >> 6, lane = t & 63;               // w: 0..3 = m-quarter
    int xcd = bid & 7, j = bid >> 3;             // j: 0..63
    int nt = ((j & 15) << 3) | xcd;              // 0..127
    int chunk = j >> 4;                          // 0..3 -> mts chunk,chunk+4,...
    int n0 = nt * 128;

    // stage A panel: 64 KB contiguous in frag-order; wave w covers 16 KB
    {
        const __hip_bfloat16* src = A16f + ((size_t)n0 << 8) + w * 8192 + lane * 8;
        __hip_bfloat16* dst = &As[w * 8192];
        #pragma unroll
        for (int i = 0; i < 16; ++i)
            __builtin_amdgcn_global_load_lds((const AS1 unsigned int*)(src + i * 512),
                                             (AS3 unsigned int*)(dst + i * 512), 16, 0, 0);
    }
    __syncthreads();

    int colL = lane & 15, rgrp = (lane >> 4) * 4;
    int p = 0;
    for (int mt = chunk; mt < MT_; mt += 4, p ^= 1) {
        floatx4 acc[8][4];
        #pragma unroll
        for (int i = 0; i < 8; ++i)
            #pragma unroll
            for (int j2 = 0; j2 < 4; ++j2) acc[i][j2] = (floatx4){0.f, 0.f, 0.f, 0.f};

        // wave w owns m-frag rows mt*16 + w*4 + {0..3}
        const bf16x8* Bp = (const bf16x8*)B16 + ((size_t)(mt * 16 + w * 4) * 8) * 64 + lane;

        #pragma unroll
        for (int kt = 0; kt < 8; ++kt) {
            bf16x8 af[8], bfr[4];
            #pragma unroll
            for (int ni = 0; ni < 8; ++ni)
                af[ni] = *(const bf16x8*)&As[(ni * 8 + kt) * 512 + lane * 8];
            #pragma unroll
            for (int mi = 0; mi < 4; ++mi)
                bfr[mi] = Bp[(size_t)(mi * 8 + kt) * 64];
            __builtin_amdgcn_s_setprio(1);
            #pragma unroll
            for (int ni = 0; ni < 8; ++ni)
                #pragma unroll
                for (int mi = 0; mi < 4; ++mi)
                    acc[ni][mi] = __builtin_amdgcn_mfma_f32_16x16x32_bf16(af[ni], bfr[mi], acc[ni][mi], 0, 0, 0);
            __builtin_amdgcn_s_setprio(0);
        }

        // epilogue: E = exp(2*cos) -> per-wave row-sums over its 64 cols
        #pragma unroll
        for (int ni = 0; ni < 8; ++ni) {
            float racc[4];
            #pragma unroll
            for (int r = 0; r < 4; ++r) racc[r] = 0.f;
            #pragma unroll
            for (int mi = 0; mi < 4; ++mi)
                #pragma unroll
                for (int r = 0; r < 4; ++r)
                    racc[r] += __expf(2.0f * acc[ni][mi][r]);
            #pragma unroll
            for (int r = 0; r < 4; ++r) {
                float s = racc[r];
                s += __shfl_xor(s, 1, 64);
                s += __shfl_xor(s, 2, 64);
                s += __shfl_xor(s, 4, 64);
                s += __shfl_xor(s, 8, 64);
                if (colL == 0) totals_s[p][w][ni * 16 + rgrp + r] = s;
            }
        }
        // lgkm-only barrier: LDS writes visible, global (B) loads stay in flight
        asm volatile("s_waitcnt lgkmcnt(0)\n\ts_barrier" ::: "memory");
        if (t < 128) {
            float s = totals_s[p][0][t] + totals_s[p][1][t]
                    + totals_s[p][2][t] + totals_s[p][3][t];
            totpart[(size_t)mt * N_ + n0 + t] = s;
        }
        // no second barrier: next iteration writes the other buffer; the next
        // lgkm-barrier separates this iteration's reads from the p-reuse writes.
    }
}

// ---------------- kernel 3: pass-2 own-class recompute + terms + final ----------------
__global__ __launch_bounds__(512) void k_pass2(const __hip_bfloat16* __restrict__ A16f,
                                               const __hip_bfloat16* __restrict__ B16,
                                               const int* __restrict__ ccnt,
                                               const int* __restrict__ pix,
                                               const float* __restrict__ totpart,
                                               const int* __restrict__ wmem,
                                               float* __restrict__ class_sum,
                                               int* __restrict__ done,
                                               float* __restrict__ out) {
    __shared__ __hip_bfloat16 As[64 * 256];   // 32 KB, fragment order
    __shared__ int pidx_s[64];
    __shared__ float tot_s[64];
    __shared__ int wm_s[64];
    __shared__ float bsum_s[8][64];
    __shared__ float wsum_s[8][64];
    __shared__ float down_s[64];
    __shared__ float term_s[64];

    int c = blockIdx.x, tile = blockIdx.y;
    int cnt = ccnt[c];
    int t = threadIdx.x, ws = t >> 6, lane = t & 63;

    if (tile * 64 >= cnt) {                    // empty tile: still hit the counter
        if (t == 0) {
            __threadfence();
            int old = atomicAdd(done, 1);
            if (old == P2_BLOCKS - 1) {
                float loss = 0.f, kc = 0.f;
                for (int cc = 0; cc < C_; ++cc) {
                    int cn = ccnt[cc];
                    float sc = atomicAdd(&class_sum[cc], 0.f);
                    if (cn > 0) { loss += sc / ((float)cn * (float)S_); kc += 1.f; }
                }
                out[0] = loss / fmaxf(kc, 1.f);
            }
        }
        return;
    }

    if (t < 64) {
        int i = tile * 64 + t;
        int p = pix[c * N_ + (i < cnt ? i : 0)];
        pidx_s[t] = p;
        wm_s[t]   = wmem[p];
    }
    __syncthreads();

    // inline total: 8 threads per pixel sum the 38 partial slots
    {
        int px = t >> 3, g = t & 7;
        int p = pidx_s[px];
        float s = 0.f;
        for (int i = g; i < MT_; i += 8) s += totpart[(size_t)i * N_ + p];
        s += __shfl_xor(s, 1, 64);
        s += __shfl_xor(s, 2, 64);
        s += __shfl_xor(s, 4, 64);
        if (g == 0) tot_s[px] = s;
    }

    // gather A rows (frag-order chunks) into LDS fragment order
    #pragma unroll
    for (int s2 = 0; s2 < 4; ++s2) {
        int g = t + 512 * s2;          // 0..2047: 64 rows x 32 16B-chunks
        int row = g >> 5, f = (g & 31) * 8;
        float4 v = *(const float4*)&A16f[fragoff(pidx_s[row], f)];
        *(float4*)&As[fragoff(row, f)] = v;
    }
    __syncthreads();

    floatx4 acc[4][4];
    #pragma unroll
    for (int i = 0; i < 4; ++i)
        #pragma unroll
        for (int j = 0; j < 4; ++j) acc[i][j] = (floatx4){0.f, 0.f, 0.f, 0.f};

    const bf16x8* Bp = (const bf16x8*)B16 + ((size_t)(c * 32 + ws * 4) * 8) * 64 + lane;
    #pragma unroll
    for (int kt = 0; kt < 8; ++kt) {
        bf16x8 af[4], bfr[4];
        #pragma unroll
        for (int ni = 0; ni < 4; ++ni)
            af[ni] = *(const bf16x8*)&As[(ni * 8 + kt) * 512 + lane * 8];
        #pragma unroll
        for (int mi = 0; mi < 4; ++mi) bfr[mi] = Bp[(size_t)(mi * 8 + kt) * 64];
        #pragma unroll
        for (int ni = 0; ni < 4; ++ni)
            #pragma unroll
            for (int mi = 0; mi < 4; ++mi)
                acc[ni][mi] = __builtin_amdgcn_mfma_f32_16x16x32_bf16(af[ni], bfr[mi], acc[ni][mi], 0, 0, 0);
    }

    int colL = lane & 15, rgrp = (lane >> 4) * 4;
    float Ev[4][4][4];
    #pragma unroll
    for (int ni = 0; ni < 4; ++ni)
        #pragma unroll
        for (int mi = 0; mi < 4; ++mi)
            #pragma unroll
            for (int r = 0; r < 4; ++r)
                Ev[ni][mi][r] = __expf(2.0f * acc[ni][mi][r]);

    #pragma unroll
    for (int ni = 0; ni < 4; ++ni)
        #pragma unroll
        for (int r = 0; r < 4; ++r) {
            float s = Ev[ni][0][r] + Ev[ni][1][r] + Ev[ni][2][r] + Ev[ni][3][r];
            s += __shfl_xor(s, 1, 64);
            s += __shfl_xor(s, 2, 64);
            s += __shfl_xor(s, 4, 64);
            s += __shfl_xor(s, 8, 64);
            if (colL == 0) bsum_s[ws][ni * 16 + rgrp + r] = s;
        }
    __syncthreads();
    if (t < 64) {
        float bs = 0.f;
        #pragma unroll
        for (int w2 = 0; w2 < 8; ++w2) bs += bsum_s[w2][t];
        down_s[t] = tot_s[t] - bs;
    }
    __syncthreads();

    #pragma unroll
    for (int ni = 0; ni < 4; ++ni)
        #pragma unroll
        for (int r = 0; r < 4; ++r) {
            int row = ni * 16 + rgrp + r;
            bool sel = (wm_s[row] == 1) ? (ws < 4) : (ws >= 4);
            float tt = 0.f;
            if (sel) {
                float dwn = down_s[row];
                #pragma unroll
                for (int mi = 0; mi < 4; ++mi) {
                    float pv = Ev[ni][mi][r];
                    tt += -logf(pv / (pv + dwn + 1e-12f) + 1e-12f);
                }
            }
            tt += __shfl_xor(tt, 1, 64);
            tt += __shfl_xor(tt, 2, 64);
            tt += __shfl_xor(tt, 4, 64);
            tt += __shfl_xor(tt, 8, 64);
            if (colL == 0) wsum_s[ws][row] = tt;
        }
    __syncthreads();
    if (t < 64) {
        int i = tile * 64 + t;
        float s = 0.f;
        if (i < cnt) {
            #pragma unroll
            for (int w2 = 0; w2 < 8; ++w2) s += wsum_s[w2][t];
        }
        term_s[t] = s;
    }
    __syncthreads();
    if (t < 64) {
        float s = term_s[t];
        #pragma unroll
        for (int off = 1; off < 64; off <<= 1) s += __shfl_xor(s, off, 64);
        if (t == 0) {
            atomicAdd(&class_sum[c], s);
            __threadfence();
            int old = atomicAdd(done, 1);
            if (old == P2_BLOCKS - 1) {
                float loss = 0.f, kc = 0.f;
                for (int cc = 0; cc < C_; ++cc) {
                    int cn = ccnt[cc];
                    float sc = atomicAdd(&class_sum[cc], 0.f);
                    if (cn > 0) { loss += sc / ((float)cn * (float)S_); kc += 1.f; }
                }
                out[0] = loss / fmaxf(kc, 1.f);
            }
        }
    }
}

extern "C" void kernel_launch(void* const* d_in, const int* in_sizes, int n_in,
                              void* d_out, int out_size, void* d_ws, size_t ws_size,
                              hipStream_t stream) {
    const float* mem    = (const float*)d_in[0];
    const float* pred   = (const float*)d_in[1];
    const int*   labels = (const int*)  d_in[2];
    const int*   mask   = (const int*)  d_in[3];
    const int*   wmem   = (const int*)  d_in[4];
    float* out = (float*)d_out;

    float* ws = (float*)d_ws;
    float* totpart   = ws;                            // 38*N_ = 622,592 floats
    int*   ctrl      = (int*)(ws + 622592);           // 40 words: ccnt|class_sum|done
    int*   ccnt      = ctrl;                          // 19
    float* class_sum = (float*)(ctrl + 19);           // 19
    int*   done      = ctrl + 38;                     // 1
    int*   pix       = (int*)(ws + 622640);           // 19*N_ ints
    __hip_bfloat16* A16f = (__hip_bfloat16*)(ws + 933936);    // 8 MB (frag order)
    __hip_bfloat16* B16  = (__hip_bfloat16*)(ws + 3031088);   // 4.86 MB (frag order)

    hipMemsetAsync(ctrl, 0, 40 * sizeof(int), stream);

    k_prep<<<PREP_BUCKET0 + 64, 256, 0, stream>>>(pred, mem, A16f, B16,
                                                  labels, mask, ccnt, pix);

    k_pass1<<<GEMM_BLKS, 256, 0, stream>>>(A16f, B16, totpart);

    dim3 g2(C_, 16);
    k_pass2<<<g2, 512, 0, stream>>>(A16f, B16, ccnt, pix, totpart, wmem,
                                    class_sum, done, out);
}

// Round 6
// 177.199 us; speedup vs baseline: 1.2638x; 1.2638x over previous
//
#include <hip/hip_runtime.h>
#include <hip/hip_bf16.h>
#include <math.h>

#define B_ 4
#define F_ 256
#define C_ 19
#define S_ 256
#define N_ 16384
#define M_ 9728
#define MT_ 38           // m-tiles (256 cols each) in pass1
#define PREP_PRED 256
#define PREP_BUCKET0 2688   // 256 + 2432
#define GEMM_BLKS 512
#define P2_BLOCKS (C_ * 16)

typedef __bf16 bf16_t;
typedef bf16_t bf16x8 __attribute__((ext_vector_type(8)));
typedef float floatx4 __attribute__((ext_vector_type(4)));

#define AS1 __attribute__((address_space(1)))
#define AS3 __attribute__((address_space(3)))

// Fragment-order layout: element (row, f) lives at
//   ((row>>4)*8 + (f>>5))*512 + ((f>>3)&3)*128 + (row&15)*8 + (f&7)
__device__ inline size_t fragoff(int row, int f) {
    return ((size_t)((row >> 4) * 8 + (f >> 5))) * 512
         + (size_t)((((f >> 3) & 3) * 128) + ((row & 15) * 8) + (f & 7));
}

// ---------------- kernel 1: prep (convert + normalize) + bucketing ----------
// ctrl (ccnt/class_sum/done) zeroed by hipMemsetAsync before this kernel.
__global__ __launch_bounds__(256) void k_prep(const float* __restrict__ pred,
                                              const float* __restrict__ mem,
                                              __hip_bfloat16* __restrict__ A16f,
                                              __hip_bfloat16* __restrict__ B16,
                                              const int* __restrict__ labels,
                                              const int* __restrict__ mask,
                                              int* __restrict__ ccnt,
                                              int* __restrict__ pix) {
    int bid = blockIdx.x;
    int t = threadIdx.x;
    if (bid < PREP_PRED) {
        __shared__ float part[4][64];
        __shared__ float invf_s[64];
        int b = bid >> 6, hw0 = (bid & 63) * 64;
        int j = t & 63, q = t >> 6;
        int n0 = b * 4096 + hw0;

        const float* base = pred + ((size_t)b * F_ + q * 64) * 4096 + hw0 + j;
        float v[64];
        float s = 0.f;
        #pragma unroll
        for (int i = 0; i < 64; ++i) {
            float x = base[(size_t)i * 4096];
            v[i] = x;
            s += x * x;
        }
        part[q][j] = s;
        __syncthreads();
        if (t < 64) invf_s[t] = 1.0f / sqrtf(part[0][t] + part[1][t] + part[2][t] + part[3][t]);
        __syncthreads();
        float invf = invf_s[j];
        #pragma unroll
        for (int c = 0; c < 8; ++c) {
            int f = q * 64 + c * 8;
            __hip_bfloat16 tmp[8];
            #pragma unroll
            for (int u = 0; u < 8; ++u) tmp[u] = __float2bfloat16(v[c * 8 + u] * invf);
            *(float4*)&A16f[fragoff(n0 + j, f)] = *(float4*)tmp;
        }
    } else if (bid < PREP_BUCKET0) {
        int row  = (bid - PREP_PRED) * 4 + (t >> 6);
        int lane = t & 63;
        float4 a = ((const float4*)(mem + (size_t)row * F_))[lane];
        float s = a.x*a.x + a.y*a.y + a.z*a.z + a.w*a.w;
        #pragma unroll
        for (int off = 32; off; off >>= 1) s += __shfl_xor(s, off, 64);
        float invm = 1.0f / sqrtf(s);
        __hip_bfloat16 tmp[4];
        tmp[0] = __float2bfloat16(a.x * invm);
        tmp[1] = __float2bfloat16(a.y * invm);
        tmp[2] = __float2bfloat16(a.z * invm);
        tmp[3] = __float2bfloat16(a.w * invm);
        *(float2*)&B16[fragoff(row, lane * 4)] = *(float2*)tmp;
    } else {                                   // ---- bucketing, 256 px/block
        __shared__ int hist[C_], base_s[C_], cur[C_];
        int n0 = (bid - PREP_BUCKET0) * 256;
        if (t < C_) { hist[t] = 0; cur[t] = 0; }
        __syncthreads();
        int myc = labels[n0 + t];
        int mym = mask[n0 + t];
        if (mym) atomicAdd(&hist[myc], 1);
        __syncthreads();
        if (t < C_) base_s[t] = atomicAdd(&ccnt[t], hist[t]);
        __syncthreads();
        if (mym) {
            int o = atomicAdd(&cur[myc], 1);
            pix[myc * N_ + base_s[myc] + o] = n0 + t;
        }
    }
}

// ---------------- kernel 2: pass-1 GEMM over MASKED pixels only ----------
// Compact slot space: slot s -> class c (prefix of ccnt), pixel pix[c][s-pre].
// nt_total = ceil(cnt_all/128) panels (~64); NCHUNK = min(512/nt_total, 38);
// 512 blocks all busy, each: gather-stage 128 rows into LDS (frag order),
// then ~38/NCHUNK mts of the proven 8-wave 64x64 structure (acc[4][4]).
// totpart indexed by [mt][slot].
__global__ __launch_bounds__(512, 4) void k_pass1(const __hip_bfloat16* __restrict__ A16f,
                                                  const __hip_bfloat16* __restrict__ B16,
                                                  const int* __restrict__ ccnt,
                                                  const int* __restrict__ pix,
                                                  float* __restrict__ totpart) {
    __shared__ __hip_bfloat16 As[128 * 256];     // 64 KB
    __shared__ float totals_s[2][4][128];        // 4 KB (double-buffered)
    __shared__ int pidx_s[128];
    int bid = blockIdx.x;
    int t = threadIdx.x;
    int w = t >> 6, lane = t & 63;
    int nh = w & 1, mq = w >> 1;

    // ---- dynamic decomposition from ccnt
    int cnt_all = 0;
    #pragma unroll
    for (int cc = 0; cc < C_; ++cc) cnt_all += ccnt[cc];
    int nt_total = (cnt_all + 127) >> 7;
    if (nt_total == 0) return;
    int nchunk = GEMM_BLKS / nt_total;
    if (nchunk > MT_) nchunk = MT_;
    if (bid >= nt_total * nchunk) return;
    int panel = bid % nt_total;
    int chunk = bid / nt_total;
    int slot0 = panel * 128;

    // ---- resolve this panel's 128 compact slots -> pixel ids
    if (t < 128) {
        int slot = slot0 + t;
        int run = 0, pixid = 0;
        #pragma unroll
        for (int cc = 0; cc < C_; ++cc) {
            int cn = ccnt[cc];
            if (slot >= run && slot < run + cn) pixid = pix[cc * N_ + slot - run];
            run += cn;
        }
        if (slot >= cnt_all) pixid = 0;   // pad rows: any valid A16f row
        pidx_s[t] = pixid;
    }
    __syncthreads();

    // ---- gather-stage A panel (64 KB) in fragment order
    // LDS 16B-chunk k corresponds to (row = (k>>9)*16 | (k&15),
    //                                 f   = ((k>>6)&7)*32 + ((k>>4)&3)*8)
    #pragma unroll
    for (int s = 0; s < 8; ++s) {
        int k = t + 512 * s;               // 0..4095
        int row = ((k >> 9) << 4) | (k & 15);
        int f   = ((k >> 6) & 7) * 32 + ((k >> 4) & 3) * 8;
        float4 v = *(const float4*)&A16f[fragoff(pidx_s[row], f)];
        ((float4*)As)[k] = v;
    }
    __syncthreads();

    int colL = lane & 15, rgrp = (lane >> 4) * 4;
    int p = 0;
    for (int mt = chunk; mt < MT_; mt += nchunk, p ^= 1) {
        floatx4 acc[4][4];
        #pragma unroll
        for (int i = 0; i < 4; ++i)
            #pragma unroll
            for (int j2 = 0; j2 < 4; ++j2) acc[i][j2] = (floatx4){0.f, 0.f, 0.f, 0.f};

        const bf16x8* Bp = (const bf16x8*)B16 + ((size_t)(mt * 16 + mq * 4) * 8) * 64 + lane;

        #pragma unroll
        for (int kt = 0; kt < 8; ++kt) {
            bf16x8 af[4], bfr[4];
            #pragma unroll
            for (int ni = 0; ni < 4; ++ni)
                af[ni] = *(const bf16x8*)&As[((nh * 4 + ni) * 8 + kt) * 512 + lane * 8];
            #pragma unroll
            for (int mi = 0; mi < 4; ++mi)
                bfr[mi] = Bp[(size_t)(mi * 8 + kt) * 64];
            __builtin_amdgcn_s_setprio(1);
            #pragma unroll
            for (int ni = 0; ni < 4; ++ni)
                #pragma unroll
                for (int mi = 0; mi < 4; ++mi)
                    acc[ni][mi] = __builtin_amdgcn_mfma_f32_16x16x32_bf16(af[ni], bfr[mi], acc[ni][mi], 0, 0, 0);
            __builtin_amdgcn_s_setprio(0);
        }

        // epilogue: E = exp(2*cos) -> wave row-sums -> LDS combine over 4 mq
        float racc[4][4];
        #pragma unroll
        for (int ni = 0; ni < 4; ++ni)
            #pragma unroll
            for (int r = 0; r < 4; ++r) racc[ni][r] = 0.f;
        #pragma unroll
        for (int ni = 0; ni < 4; ++ni)
            #pragma unroll
            for (int mi = 0; mi < 4; ++mi)
                #pragma unroll
                for (int r = 0; r < 4; ++r)
                    racc[ni][r] += __expf(2.0f * acc[ni][mi][r]);

        #pragma unroll
        for (int ni = 0; ni < 4; ++ni)
            #pragma unroll
            for (int r = 0; r < 4; ++r) {
                float s = racc[ni][r];
                s += __shfl_xor(s, 1, 64);
                s += __shfl_xor(s, 2, 64);
                s += __shfl_xor(s, 4, 64);
                s += __shfl_xor(s, 8, 64);
                if (colL == 0) totals_s[p][mq][nh * 64 + ni * 16 + rgrp + r] = s;
            }
        // lgkm-only barrier: LDS writes visible, global (B) loads stay in flight
        asm volatile("s_waitcnt lgkmcnt(0)\n\ts_barrier" ::: "memory");
        if (t < 128)
            totpart[(size_t)mt * N_ + slot0 + t] =
                totals_s[p][0][t] + totals_s[p][1][t] + totals_s[p][2][t] + totals_s[p][3][t];
        // next iteration writes the other totals_s buffer; its lgkm-barrier
        // orders these reads before the buffer's reuse.
    }
}

// ---------------- kernel 3: pass-2 own-class recompute + terms + final ----------------
__global__ __launch_bounds__(512) void k_pass2(const __hip_bfloat16* __restrict__ A16f,
                                               const __hip_bfloat16* __restrict__ B16,
                                               const int* __restrict__ ccnt,
                                               const int* __restrict__ pix,
                                               const float* __restrict__ totpart,
                                               const int* __restrict__ wmem,
                                               float* __restrict__ class_sum,
                                               int* __restrict__ done,
                                               float* __restrict__ out) {
    __shared__ __hip_bfloat16 As[64 * 256];   // 32 KB, fragment order
    __shared__ int pidx_s[64];
    __shared__ float tot_s[64];
    __shared__ int wm_s[64];
    __shared__ float bsum_s[8][64];
    __shared__ float wsum_s[8][64];
    __shared__ float down_s[64];
    __shared__ float term_s[64];

    int c = blockIdx.x, tile = blockIdx.y;
    int cnt = ccnt[c];
    int t = threadIdx.x, ws = t >> 6, lane = t & 63;

    if (tile * 64 >= cnt) {                    // empty tile: still hit the counter
        if (t == 0) {
            __threadfence();
            int old = atomicAdd(done, 1);
            if (old == P2_BLOCKS - 1) {
                float loss = 0.f, kc = 0.f;
                for (int cc = 0; cc < C_; ++cc) {
                    int cn = ccnt[cc];
                    float sc = atomicAdd(&class_sum[cc], 0.f);
                    if (cn > 0) { loss += sc / ((float)cn * (float)S_); kc += 1.f; }
                }
                out[0] = loss / fmaxf(kc, 1.f);
            }
        }
        return;
    }

    // compact-slot base of this tile (prefix of ccnt)
    int pre = 0;
    #pragma unroll
    for (int cc = 0; cc < C_; ++cc) if (cc < c) pre += ccnt[cc];
    int slot0 = pre + tile * 64;

    if (t < 64) {
        int i = tile * 64 + t;
        int p = pix[c * N_ + (i < cnt ? i : 0)];
        pidx_s[t] = p;
        wm_s[t]   = wmem[p];
    }
    __syncthreads();

    // inline total: 8 threads per pixel sum the 38 partial slots (slot-contiguous)
    {
        int px = t >> 3, g = t & 7;
        float s = 0.f;
        for (int i = g; i < MT_; i += 8) s += totpart[(size_t)i * N_ + slot0 + px];
        s += __shfl_xor(s, 1, 64);
        s += __shfl_xor(s, 2, 64);
        s += __shfl_xor(s, 4, 64);
        if (g == 0) tot_s[px] = s;
    }

    // gather A rows (frag-order chunks) into LDS fragment order
    #pragma unroll
    for (int s2 = 0; s2 < 4; ++s2) {
        int g = t + 512 * s2;          // 0..2047: 64 rows x 32 16B-chunks
        int row = g >> 5, f = (g & 31) * 8;
        float4 v = *(const float4*)&A16f[fragoff(pidx_s[row], f)];
        *(float4*)&As[fragoff(row, f)] = v;
    }
    __syncthreads();

    floatx4 acc[4][4];
    #pragma unroll
    for (int i = 0; i < 4; ++i)
        #pragma unroll
        for (int j = 0; j < 4; ++j) acc[i][j] = (floatx4){0.f, 0.f, 0.f, 0.f};

    const bf16x8* Bp = (const bf16x8*)B16 + ((size_t)(c * 32 + ws * 4) * 8) * 64 + lane;
    #pragma unroll
    for (int kt = 0; kt < 8; ++kt) {
        bf16x8 af[4], bfr[4];
        #pragma unroll
        for (int ni = 0; ni < 4; ++ni)
            af[ni] = *(const bf16x8*)&As[(ni * 8 + kt) * 512 + lane * 8];
        #pragma unroll
        for (int mi = 0; mi < 4; ++mi) bfr[mi] = Bp[(size_t)(mi * 8 + kt) * 64];
        #pragma unroll
        for (int ni = 0; ni < 4; ++ni)
            #pragma unroll
            for (int mi = 0; mi < 4; ++mi)
                acc[ni][mi] = __builtin_amdgcn_mfma_f32_16x16x32_bf16(af[ni], bfr[mi], acc[ni][mi], 0, 0, 0);
    }

    int colL = lane & 15, rgrp = (lane >> 4) * 4;
    float Ev[4][4][4];
    #pragma unroll
    for (int ni = 0; ni < 4; ++ni)
        #pragma unroll
        for (int mi = 0; mi < 4; ++mi)
            #pragma unroll
            for (int r = 0; r < 4; ++r)
                Ev[ni][mi][r] = __expf(2.0f * acc[ni][mi][r]);

    #pragma unroll
    for (int ni = 0; ni < 4; ++ni)
        #pragma unroll
        for (int r = 0; r < 4; ++r) {
            float s = Ev[ni][0][r] + Ev[ni][1][r] + Ev[ni][2][r] + Ev[ni][3][r];
            s += __shfl_xor(s, 1, 64);
            s += __shfl_xor(s, 2, 64);
            s += __shfl_xor(s, 4, 64);
            s += __shfl_xor(s, 8, 64);
            if (colL == 0) bsum_s[ws][ni * 16 + rgrp + r] = s;
        }
    __syncthreads();
    if (t < 64) {
        float bs = 0.f;
        #pragma unroll
        for (int w2 = 0; w2 < 8; ++w2) bs += bsum_s[w2][t];
        down_s[t] = tot_s[t] - bs;
    }
    __syncthreads();

    #pragma unroll
    for (int ni = 0; ni < 4; ++ni)
        #pragma unroll
        for (int r = 0; r < 4; ++r) {
            int row = ni * 16 + rgrp + r;
            bool sel = (wm_s[row] == 1) ? (ws < 4) : (ws >= 4);
            float tt = 0.f;
            if (sel) {
                float dwn = down_s[row];
                #pragma unroll
                for (int mi = 0; mi < 4; ++mi) {
                    float pv = Ev[ni][mi][r];
                    tt += -logf(pv / (pv + dwn + 1e-12f) + 1e-12f);
                }
            }
            tt += __shfl_xor(tt, 1, 64);
            tt += __shfl_xor(tt, 2, 64);
            tt += __shfl_xor(tt, 4, 64);
            tt += __shfl_xor(tt, 8, 64);
            if (colL == 0) wsum_s[ws][row] = tt;
        }
    __syncthreads();
    if (t < 64) {
        int i = tile * 64 + t;
        float s = 0.f;
        if (i < cnt) {
            #pragma unroll
            for (int w2 = 0; w2 < 8; ++w2) s += wsum_s[w2][t];
        }
        term_s[t] = s;
    }
    __syncthreads();
    if (t < 64) {
        float s = term_s[t];
        #pragma unroll
        for (int off = 1; off < 64; off <<= 1) s += __shfl_xor(s, off, 64);
        if (t == 0) {
            atomicAdd(&class_sum[c], s);
            __threadfence();
            int old = atomicAdd(done, 1);
            if (old == P2_BLOCKS - 1) {
                float loss = 0.f, kc = 0.f;
                for (int cc = 0; cc < C_; ++cc) {
                    int cn = ccnt[cc];
                    float sc = atomicAdd(&class_sum[cc], 0.f);
                    if (cn > 0) { loss += sc / ((float)cn * (float)S_); kc += 1.f; }
                }
                out[0] = loss / fmaxf(kc, 1.f);
            }
        }
    }
}

extern "C" void kernel_launch(void* const* d_in, const int* in_sizes, int n_in,
                              void* d_out, int out_size, void* d_ws, size_t ws_size,
                              hipStream_t stream) {
    const float* mem    = (const float*)d_in[0];
    const float* pred   = (const float*)d_in[1];
    const int*   labels = (const int*)  d_in[2];
    const int*   mask   = (const int*)  d_in[3];
    const int*   wmem   = (const int*)  d_in[4];
    float* out = (float*)d_out;

    float* ws = (float*)d_ws;
    float* totpart   = ws;                            // 38*N_ = 622,592 floats
    int*   ctrl      = (int*)(ws + 622592);           // 40 words: ccnt|class_sum|done
    int*   ccnt      = ctrl;                          // 19
    float* class_sum = (float*)(ctrl + 19);           // 19
    int*   done      = ctrl + 38;                     // 1
    int*   pix       = (int*)(ws + 622640);           // 19*N_ ints
    __hip_bfloat16* A16f = (__hip_bfloat16*)(ws + 933936);    // 8 MB (frag order)
    __hip_bfloat16* B16  = (__hip_bfloat16*)(ws + 3031088);   // 4.86 MB (frag order)

    hipMemsetAsync(ctrl, 0, 40 * sizeof(int), stream);

    k_prep<<<PREP_BUCKET0 + 64, 256, 0, stream>>>(pred, mem, A16f, B16,
                                                  labels, mask, ccnt, pix);

    k_pass1<<<GEMM_BLKS, 512, 0, stream>>>(A16f, B16, ccnt, pix, totpart);

    dim3 g2(C_, 16);
    k_pass2<<<g2, 512, 0, stream>>>(A16f, B16, ccnt, pix, totpart, wmem,
                                    class_sum, done, out);
}

// Round 7
// 176.347 us; speedup vs baseline: 1.2699x; 1.0048x over previous
//
#include <hip/hip_runtime.h>
#include <hip/hip_bf16.h>
#include <math.h>

#define B_ 4
#define F_ 256
#define C_ 19
#define S_ 256
#define N_ 16384
#define M_ 9728
#define MT_ 38           // m-tiles (256 cols each) in pass1
#define NP_ 18816        // max padded compact slots: N_ + C_*128
#define PREP_PRED 256
#define PREP_BUCKET0 2688   // 256 + 2432
#define GEMM_BLKS 512
#define P2_BLOCKS (C_ * 16)

typedef __bf16 bf16_t;
typedef bf16_t bf16x8 __attribute__((ext_vector_type(8)));
typedef float floatx4 __attribute__((ext_vector_type(4)));

#define AS1 __attribute__((address_space(1)))
#define AS3 __attribute__((address_space(3)))

// Fragment-order layout: element (row, f) lives at
//   ((row>>4)*8 + (f>>5))*512 + ((f>>3)&3)*128 + (row&15)*8 + (f&7)
__device__ inline size_t fragoff(int row, int f) {
    return ((size_t)((row >> 4) * 8 + (f >> 5))) * 512
         + (size_t)((((f >> 3) & 3) * 128) + ((row & 15) * 8) + (f & 7));
}

// ---------------- kernel 1: prep (convert + normalize) + bucketing ----------
__global__ __launch_bounds__(256) void k_prep(const float* __restrict__ pred,
                                              const float* __restrict__ mem,
                                              __hip_bfloat16* __restrict__ A16f,
                                              __hip_bfloat16* __restrict__ B16,
                                              const int* __restrict__ labels,
                                              const int* __restrict__ mask,
                                              int* __restrict__ ccnt,
                                              int* __restrict__ pix) {
    int bid = blockIdx.x;
    int t = threadIdx.x;
    if (bid < PREP_PRED) {
        __shared__ float part[4][64];
        __shared__ float invf_s[64];
        int b = bid >> 6, hw0 = (bid & 63) * 64;
        int j = t & 63, q = t >> 6;
        int n0 = b * 4096 + hw0;

        const float* base = pred + ((size_t)b * F_ + q * 64) * 4096 + hw0 + j;
        float v[64];
        float s = 0.f;
        #pragma unroll
        for (int i = 0; i < 64; ++i) {
            float x = base[(size_t)i * 4096];
            v[i] = x;
            s += x * x;
        }
        part[q][j] = s;
        __syncthreads();
        if (t < 64) invf_s[t] = 1.0f / sqrtf(part[0][t] + part[1][t] + part[2][t] + part[3][t]);
        __syncthreads();
        float invf = invf_s[j];
        #pragma unroll
        for (int c = 0; c < 8; ++c) {
            int f = q * 64 + c * 8;
            __hip_bfloat16 tmp[8];
            #pragma unroll
            for (int u = 0; u < 8; ++u) tmp[u] = __float2bfloat16(v[c * 8 + u] * invf);
            *(float4*)&A16f[fragoff(n0 + j, f)] = *(float4*)tmp;
        }
    } else if (bid < PREP_BUCKET0) {
        int row  = (bid - PREP_PRED) * 4 + (t >> 6);
        int lane = t & 63;
        float4 a = ((const float4*)(mem + (size_t)row * F_))[lane];
        float s = a.x*a.x + a.y*a.y + a.z*a.z + a.w*a.w;
        #pragma unroll
        for (int off = 32; off; off >>= 1) s += __shfl_xor(s, off, 64);
        float invm = 1.0f / sqrtf(s);
        __hip_bfloat16 tmp[4];
        tmp[0] = __float2bfloat16(a.x * invm);
        tmp[1] = __float2bfloat16(a.y * invm);
        tmp[2] = __float2bfloat16(a.z * invm);
        tmp[3] = __float2bfloat16(a.w * invm);
        *(float2*)&B16[fragoff(row, lane * 4)] = *(float2*)tmp;
    } else {                                   // ---- bucketing, 256 px/block
        __shared__ int hist[C_], base_s[C_], cur[C_];
        int n0 = (bid - PREP_BUCKET0) * 256;
        if (t < C_) { hist[t] = 0; cur[t] = 0; }
        __syncthreads();
        int myc = labels[n0 + t];
        int mym = mask[n0 + t];
        if (mym) atomicAdd(&hist[myc], 1);
        __syncthreads();
        if (t < C_) base_s[t] = atomicAdd(&ccnt[t], hist[t]);
        __syncthreads();
        if (mym) {
            int o = atomicAdd(&cur[myc], 1);
            pix[myc * N_ + base_s[myc] + o] = n0 + t;
        }
    }
}

// ---------------- kernel 1b: compact gather (once) ----------
// Class-sorted compact buffer, each class padded to 128 slots. Pad slots copy
// pixel 0's row (finite garbage, never read downstream). Dest writes linear.
__global__ __launch_bounds__(256) void k_compact(const __hip_bfloat16* __restrict__ A16f,
                                                 const int* __restrict__ ccnt,
                                                 const int* __restrict__ pix,
                                                 __hip_bfloat16* __restrict__ A16c) {
    __shared__ int pidx_s[64];
    int bid = blockIdx.x, t = threadIdx.x;
    int slot0 = bid * 64;
    int slot = slot0 + (t & 63);
    int run = 0, pixid = 0;
    #pragma unroll
    for (int cc = 0; cc < C_; ++cc) {
        int cn = ccnt[cc];
        if (slot >= run && slot < run + cn) pixid = pix[cc * N_ + slot - run];
        run += (cn + 127) & ~127;
    }
    if (slot0 >= run) return;                  // run == padded_total
    if (t < 64) pidx_s[t] = pixid;
    __syncthreads();
    #pragma unroll
    for (int s = 0; s < 8; ++s) {
        int k = t + 256 * s;                   // 0..2047: 16B chunks of 64-row block
        int row = ((k >> 9) << 4) | (k & 15);
        int f   = ((k >> 6) & 7) * 32 + ((k >> 4) & 3) * 8;
        float4 v = *(const float4*)&A16f[fragoff(pidx_s[row], f)];
        *(float4*)&A16c[((size_t)slot0 << 8) + (size_t)k * 8] = v;
    }
}

// ---------------- kernel 2: pass-1 GEMM over compact slots ----------
// nt_total = padded_total/128 panels; nchunk = min(512/nt_total, 38).
// A panel staged linearly from A16c via global_load_lds (proven R1 structure:
// 8 waves of 64x64, acc[4][4]); lgkm-only combine barrier per mt.
__global__ __launch_bounds__(512, 4) void k_pass1(const __hip_bfloat16* __restrict__ A16c,
                                                  const __hip_bfloat16* __restrict__ B16,
                                                  const int* __restrict__ ccnt,
                                                  float* __restrict__ totpart) {
    __shared__ __hip_bfloat16 As[128 * 256];     // 64 KB
    __shared__ float totals_s[2][4][128];        // 4 KB (double-buffered)
    int bid = blockIdx.x;
    int t = threadIdx.x;
    int w = t >> 6, lane = t & 63;
    int nh = w & 1, mq = w >> 1;

    int padded_total = 0;
    #pragma unroll
    for (int cc = 0; cc < C_; ++cc) padded_total += (ccnt[cc] + 127) & ~127;
    int nt_total = padded_total >> 7;
    if (nt_total == 0) return;
    int nchunk = GEMM_BLKS / nt_total;
    if (nchunk > MT_) nchunk = MT_;
    if (nchunk < 1) nchunk = 1;
    if (bid >= nt_total * nchunk) return;
    int panel = bid % nt_total;
    int chunk = bid / nt_total;
    int slot0 = panel << 7;

    // stage A panel: 64 KB linear from compact buffer
    {
        const __hip_bfloat16* src = A16c + ((size_t)slot0 << 8) + w * 4096 + lane * 8;
        __hip_bfloat16* dst = &As[w * 4096];
        #pragma unroll
        for (int i = 0; i < 8; ++i)
            __builtin_amdgcn_global_load_lds((const AS1 unsigned int*)(src + i * 512),
                                             (AS3 unsigned int*)(dst + i * 512), 16, 0, 0);
    }
    __syncthreads();

    int colL = lane & 15, rgrp = (lane >> 4) * 4;
    int p = 0;
    for (int mt = chunk; mt < MT_; mt += nchunk, p ^= 1) {
        floatx4 acc[4][4];
        #pragma unroll
        for (int i = 0; i < 4; ++i)
            #pragma unroll
            for (int j2 = 0; j2 < 4; ++j2) acc[i][j2] = (floatx4){0.f, 0.f, 0.f, 0.f};

        const bf16x8* Bp = (const bf16x8*)B16 + ((size_t)(mt * 16 + mq * 4) * 8) * 64 + lane;

        #pragma unroll
        for (int kt = 0; kt < 8; ++kt) {
            bf16x8 af[4], bfr[4];
            #pragma unroll
            for (int ni = 0; ni < 4; ++ni)
                af[ni] = *(const bf16x8*)&As[((nh * 4 + ni) * 8 + kt) * 512 + lane * 8];
            #pragma unroll
            for (int mi = 0; mi < 4; ++mi)
                bfr[mi] = Bp[(size_t)(mi * 8 + kt) * 64];
            __builtin_amdgcn_s_setprio(1);
            #pragma unroll
            for (int ni = 0; ni < 4; ++ni)
                #pragma unroll
                for (int mi = 0; mi < 4; ++mi)
                    acc[ni][mi] = __builtin_amdgcn_mfma_f32_16x16x32_bf16(af[ni], bfr[mi], acc[ni][mi], 0, 0, 0);
            __builtin_amdgcn_s_setprio(0);
        }

        float racc[4][4];
        #pragma unroll
        for (int ni = 0; ni < 4; ++ni)
            #pragma unroll
            for (int r = 0; r < 4; ++r) racc[ni][r] = 0.f;
        #pragma unroll
        for (int ni = 0; ni < 4; ++ni)
            #pragma unroll
            for (int mi = 0; mi < 4; ++mi)
                #pragma unroll
                for (int r = 0; r < 4; ++r)
                    racc[ni][r] += __expf(2.0f * acc[ni][mi][r]);

        #pragma unroll
        for (int ni = 0; ni < 4; ++ni)
            #pragma unroll
            for (int r = 0; r < 4; ++r) {
                float s = racc[ni][r];
                s += __shfl_xor(s, 1, 64);
                s += __shfl_xor(s, 2, 64);
                s += __shfl_xor(s, 4, 64);
                s += __shfl_xor(s, 8, 64);
                if (colL == 0) totals_s[p][mq][nh * 64 + ni * 16 + rgrp + r] = s;
            }
        // lgkm-only barrier: LDS writes visible, global (B) loads stay in flight
        asm volatile("s_waitcnt lgkmcnt(0)\n\ts_barrier" ::: "memory");
        if (t < 128)
            totpart[(size_t)mt * NP_ + slot0 + t] =
                totals_s[p][0][t] + totals_s[p][1][t] + totals_s[p][2][t] + totals_s[p][3][t];
    }
}

// ---------------- kernel 3: pass-2 own-class recompute + terms + final ----------------
__global__ __launch_bounds__(512) void k_pass2(const __hip_bfloat16* __restrict__ A16c,
                                               const __hip_bfloat16* __restrict__ B16,
                                               const int* __restrict__ ccnt,
                                               const int* __restrict__ pix,
                                               const float* __restrict__ totpart,
                                               const int* __restrict__ wmem,
                                               float* __restrict__ class_sum,
                                               int* __restrict__ done,
                                               float* __restrict__ out) {
    __shared__ __hip_bfloat16 As[64 * 256];   // 32 KB, fragment order
    __shared__ float tot_s[64];
    __shared__ int wm_s[64];
    __shared__ float bsum_s[8][64];
    __shared__ float wsum_s[8][64];
    __shared__ float down_s[64];
    __shared__ float term_s[64];

    int c = blockIdx.x, tile = blockIdx.y;
    int cnt = ccnt[c];
    int t = threadIdx.x, ws = t >> 6, lane = t & 63;

    if (tile * 64 >= cnt) {                    // empty tile: still hit the counter
        if (t == 0) {
            __threadfence();
            int old = atomicAdd(done, 1);
            if (old == P2_BLOCKS - 1) {
                float loss = 0.f, kc = 0.f;
                for (int cc = 0; cc < C_; ++cc) {
                    int cn = ccnt[cc];
                    float sc = atomicAdd(&class_sum[cc], 0.f);
                    if (cn > 0) { loss += sc / ((float)cn * (float)S_); kc += 1.f; }
                }
                out[0] = loss / fmaxf(kc, 1.f);
            }
        }
        return;
    }

    // compact-slot base (padded prefix) of this tile
    int pre = 0;
    #pragma unroll
    for (int cc = 0; cc < C_; ++cc) if (cc < c) pre += (ccnt[cc] + 127) & ~127;
    int slot0 = pre + tile * 64;

    // stage A tile: 32 KB linear from compact buffer (issued first, overlaps
    // the scattered pidx/totpart reads below)
    {
        const __hip_bfloat16* src = A16c + ((size_t)slot0 << 8) + t * 8;
        __hip_bfloat16* dst = &As[t * 8];
        #pragma unroll
        for (int i = 0; i < 4; ++i)
            __builtin_amdgcn_global_load_lds((const AS1 unsigned int*)(src + i * 4096),
                                             (AS3 unsigned int*)(dst + i * 4096), 16, 0, 0);
    }

    if (t < 64) {
        int i = tile * 64 + t;
        int p = pix[c * N_ + (i < cnt ? i : 0)];
        wm_s[t] = wmem[p];
    }

    // inline total: 8 threads per pixel sum the 38 partial slots (slot-contiguous)
    {
        int px = t >> 3, g = t & 7;
        float s = 0.f;
        for (int i = g; i < MT_; i += 8) s += totpart[(size_t)i * NP_ + slot0 + px];
        s += __shfl_xor(s, 1, 64);
        s += __shfl_xor(s, 2, 64);
        s += __shfl_xor(s, 4, 64);
        if (g == 0) tot_s[px] = s;
    }
    __syncthreads();

    floatx4 acc[4][4];
    #pragma unroll
    for (int i = 0; i < 4; ++i)
        #pragma unroll
        for (int j = 0; j < 4; ++j) acc[i][j] = (floatx4){0.f, 0.f, 0.f, 0.f};

    const bf16x8* Bp = (const bf16x8*)B16 + ((size_t)(c * 32 + ws * 4) * 8) * 64 + lane;
    #pragma unroll
    for (int kt = 0; kt < 8; ++kt) {
        bf16x8 af[4], bfr[4];
        #pragma unroll
        for (int ni = 0; ni < 4; ++ni)
            af[ni] = *(const bf16x8*)&As[(ni * 8 + kt) * 512 + lane * 8];
        #pragma unroll
        for (int mi = 0; mi < 4; ++mi) bfr[mi] = Bp[(size_t)(mi * 8 + kt) * 64];
        #pragma unroll
        for (int ni = 0; ni < 4; ++ni)
            #pragma unroll
            for (int mi = 0; mi < 4; ++mi)
                acc[ni][mi] = __builtin_amdgcn_mfma_f32_16x16x32_bf16(af[ni], bfr[mi], acc[ni][mi], 0, 0, 0);
    }

    int colL = lane & 15, rgrp = (lane >> 4) * 4;
    float Ev[4][4][4];
    #pragma unroll
    for (int ni = 0; ni < 4; ++ni)
        #pragma unroll
        for (int mi = 0; mi < 4; ++mi)
            #pragma unroll
            for (int r = 0; r < 4; ++r)
                Ev[ni][mi][r] = __expf(2.0f * acc[ni][mi][r]);

    #pragma unroll
    for (int ni = 0; ni < 4; ++ni)
        #pragma unroll
        for (int r = 0; r < 4; ++r) {
            float s = Ev[ni][0][r] + Ev[ni][1][r] + Ev[ni][2][r] + Ev[ni][3][r];
            s += __shfl_xor(s, 1, 64);
            s += __shfl_xor(s, 2, 64);
            s += __shfl_xor(s, 4, 64);
            s += __shfl_xor(s, 8, 64);
            if (colL == 0) bsum_s[ws][ni * 16 + rgrp + r] = s;
        }
    __syncthreads();
    if (t < 64) {
        float bs = 0.f;
        #pragma unroll
        for (int w2 = 0; w2 < 8; ++w2) bs += bsum_s[w2][t];
        down_s[t] = tot_s[t] - bs;
    }
    __syncthreads();

    #pragma unroll
    for (int ni = 0; ni < 4; ++ni)
        #pragma unroll
        for (int r = 0; r < 4; ++r) {
            int row = ni * 16 + rgrp + r;
            bool sel = (wm_s[row] == 1) ? (ws < 4) : (ws >= 4);
            float tt = 0.f;
            if (sel) {
                float dwn = down_s[row];
                #pragma unroll
                for (int mi = 0; mi < 4; ++mi) {
                    float pv = Ev[ni][mi][r];
                    tt += -logf(pv / (pv + dwn + 1e-12f) + 1e-12f);
                }
            }
            tt += __shfl_xor(tt, 1, 64);
            tt += __shfl_xor(tt, 2, 64);
            tt += __shfl_xor(tt, 4, 64);
            tt += __shfl_xor(tt, 8, 64);
            if (colL == 0) wsum_s[ws][row] = tt;
        }
    __syncthreads();
    if (t < 64) {
        int i = tile * 64 + t;
        float s = 0.f;
        if (i < cnt) {
            #pragma unroll
            for (int w2 = 0; w2 < 8; ++w2) s += wsum_s[w2][t];
        }
        term_s[t] = s;
    }
    __syncthreads();
    if (t < 64) {
        float s = term_s[t];
        #pragma unroll
        for (int off = 1; off < 64; off <<= 1) s += __shfl_xor(s, off, 64);
        if (t == 0) {
            atomicAdd(&class_sum[c], s);
            __threadfence();
            int old = atomicAdd(done, 1);
            if (old == P2_BLOCKS - 1) {
                float loss = 0.f, kc = 0.f;
                for (int cc = 0; cc < C_; ++cc) {
                    int cn = ccnt[cc];
                    float sc = atomicAdd(&class_sum[cc], 0.f);
                    if (cn > 0) { loss += sc / ((float)cn * (float)S_); kc += 1.f; }
                }
                out[0] = loss / fmaxf(kc, 1.f);
            }
        }
    }
}

extern "C" void kernel_launch(void* const* d_in, const int* in_sizes, int n_in,
                              void* d_out, int out_size, void* d_ws, size_t ws_size,
                              hipStream_t stream) {
    const float* mem    = (const float*)d_in[0];
    const float* pred   = (const float*)d_in[1];
    const int*   labels = (const int*)  d_in[2];
    const int*   mask   = (const int*)  d_in[3];
    const int*   wmem   = (const int*)  d_in[4];
    float* out = (float*)d_out;

    float* ws = (float*)d_ws;
    float* totpart   = ws;                            // 38*NP_ = 715,008 floats
    int*   ctrl      = (int*)(ws + 715008);           // 40 words
    int*   ccnt      = ctrl;                          // 19
    float* class_sum = (float*)(ctrl + 19);           // 19
    int*   done      = ctrl + 38;                     // 1
    int*   pix       = (int*)(ws + 715048);           // 19*N_ = 311,296 ints
    __hip_bfloat16* A16f = (__hip_bfloat16*)(ws + 1026344);   // 8 MB (frag order)
    __hip_bfloat16* A16c = (__hip_bfloat16*)(ws + 3123496);   // 9.6 MB (compact)
    __hip_bfloat16* B16  = (__hip_bfloat16*)(ws + 5531944);   // 4.98 MB (frag order)

    hipMemsetAsync(ctrl, 0, 40 * sizeof(int), stream);

    k_prep<<<PREP_BUCKET0 + 64, 256, 0, stream>>>(pred, mem, A16f, B16,
                                                  labels, mask, ccnt, pix);

    k_compact<<<NP_ / 64, 256, 0, stream>>>(A16f, ccnt, pix, A16c);

    k_pass1<<<GEMM_BLKS, 512, 0, stream>>>(A16c, B16, ccnt, totpart);

    dim3 g2(C_, 16);
    k_pass2<<<g2, 512, 0, stream>>>(A16c, B16, ccnt, pix, totpart, wmem,
                                    class_sum, done, out);
}

// Round 8
// 171.906 us; speedup vs baseline: 1.3027x; 1.0258x over previous
//
#include <hip/hip_runtime.h>
#include <hip/hip_bf16.h>
#include <math.h>

#define B_ 4
#define F_ 256
#define C_ 19
#define S_ 256
#define N_ 16384
#define M_ 9728
#define MT_ 38           // m-tiles (256 cols each) in pass1
#define NP_ 18816        // max padded compact slots: N_ + C_*128
#define PREP_PRED 256
#define PREP_TOTAL 2688  // 256 pred + 2432 mem
#define GEMM_BLKS 512
#define P2_BLOCKS (C_ * 16)

typedef __bf16 bf16_t;
typedef bf16_t bf16x8 __attribute__((ext_vector_type(8)));
typedef float floatx4 __attribute__((ext_vector_type(4)));

#define AS1 __attribute__((address_space(1)))
#define AS3 __attribute__((address_space(3)))

// Fragment-order layout: element (row, f) lives at
//   ((row>>4)*8 + (f>>5))*512 + ((f>>3)&3)*128 + (row&15)*8 + (f&7)
// For 64-aligned panels this equals panel_base*256 + 8*k with k the linear
// 16B-chunk index -> global_load_lds can stage panels linearly.
__device__ inline size_t fragoff(int row, int f) {
    return ((size_t)((row >> 4) * 8 + (f >> 5))) * 512
         + (size_t)((((f >> 3) & 3) * 128) + ((row & 15) * 8) + (f & 7));
}

// ---------------- kernel 0: bucketing + inverse slot map ----------
// ctrl zeroed by hipMemsetAsync before this kernel.
__global__ __launch_bounds__(256) void k_bucket(const int* __restrict__ labels,
                                                const int* __restrict__ mask,
                                                int* __restrict__ ccnt,
                                                int* __restrict__ pix,
                                                int* __restrict__ slotmap) {
    __shared__ int hist[C_], base_s[C_], cur[C_];
    int t = threadIdx.x;
    int n0 = blockIdx.x * 256;
    if (t < C_) { hist[t] = 0; cur[t] = 0; }
    __syncthreads();
    int myc = labels[n0 + t];
    int mym = mask[n0 + t];
    if (mym) atomicAdd(&hist[myc], 1);
    __syncthreads();
    if (t < C_) base_s[t] = atomicAdd(&ccnt[t], hist[t]);
    __syncthreads();
    int sm = -1;
    if (mym) {
        int o = atomicAdd(&cur[myc], 1);
        int pos = base_s[myc] + o;
        pix[myc * N_ + pos] = n0 + t;
        sm = (myc << 16) | pos;
    }
    slotmap[n0 + t] = sm;
}

// ---------------- kernel 1: prep -> compact A16c (masked only) + B16 ----------
__global__ __launch_bounds__(256) void k_prep(const float* __restrict__ pred,
                                              const float* __restrict__ mem,
                                              __hip_bfloat16* __restrict__ A16c,
                                              __hip_bfloat16* __restrict__ B16,
                                              const int* __restrict__ ccnt,
                                              const int* __restrict__ slotmap) {
    int bid = blockIdx.x;
    int t = threadIdx.x;
    if (bid < PREP_PRED) {
        __shared__ float part[4][64];
        __shared__ float invf_s[64];
        __shared__ int pre_s[C_];
        int b = bid >> 6, hw0 = (bid & 63) * 64;
        int j = t & 63, q = t >> 6;
        int n0 = b * 4096 + hw0;

        if (t < C_) {                       // padded class prefix (ccnt final)
            int pre = 0;
            for (int cc = 0; cc < t; ++cc) pre += (ccnt[cc] + 127) & ~127;
            pre_s[t] = pre;
        }

        const float* base = pred + ((size_t)b * F_ + q * 64) * 4096 + hw0 + j;
        float v[64];
        float s = 0.f;
        #pragma unroll
        for (int i = 0; i < 64; ++i) {
            float x = base[(size_t)i * 4096];
            v[i] = x;
            s += x * x;
        }
        part[q][j] = s;
        __syncthreads();
        if (t < 64) invf_s[t] = 1.0f / sqrtf(part[0][t] + part[1][t] + part[2][t] + part[3][t]);
        __syncthreads();
        int sm = slotmap[n0 + j];
        if (sm >= 0) {
            int slot = pre_s[sm >> 16] + (sm & 0xffff);
            float invf = invf_s[j];
            #pragma unroll
            for (int c = 0; c < 8; ++c) {
                int f = q * 64 + c * 8;
                __hip_bfloat16 tmp[8];
                #pragma unroll
                for (int u = 0; u < 8; ++u) tmp[u] = __float2bfloat16(v[c * 8 + u] * invf);
                *(float4*)&A16c[fragoff(slot, f)] = *(float4*)tmp;
            }
        }
    } else {
        int row  = (bid - PREP_PRED) * 4 + (t >> 6);
        int lane = t & 63;
        float4 a = ((const float4*)(mem + (size_t)row * F_))[lane];
        float s = a.x*a.x + a.y*a.y + a.z*a.z + a.w*a.w;
        #pragma unroll
        for (int off = 32; off; off >>= 1) s += __shfl_xor(s, off, 64);
        float invm = 1.0f / sqrtf(s);
        __hip_bfloat16 tmp[4];
        tmp[0] = __float2bfloat16(a.x * invm);
        tmp[1] = __float2bfloat16(a.y * invm);
        tmp[2] = __float2bfloat16(a.z * invm);
        tmp[3] = __float2bfloat16(a.w * invm);
        *(float2*)&B16[fragoff(row, lane * 4)] = *(float2*)tmp;
    }
}

// ---------------- kernel 2: pass-1 GEMM over compact slots ----------
// nt_total = padded_total/128 panels; nchunk = min(512/nt_total, 38).
// A panel staged linearly from A16c via global_load_lds (proven structure:
// 8 waves of 64x64, acc[4][4]); lgkm-only combine barrier per mt.
__global__ __launch_bounds__(512, 4) void k_pass1(const __hip_bfloat16* __restrict__ A16c,
                                                  const __hip_bfloat16* __restrict__ B16,
                                                  const int* __restrict__ ccnt,
                                                  float* __restrict__ totpart) {
    __shared__ __hip_bfloat16 As[128 * 256];     // 64 KB
    __shared__ float totals_s[2][4][128];        // 4 KB (double-buffered)
    int bid = blockIdx.x;
    int t = threadIdx.x;
    int w = t >> 6, lane = t & 63;
    int nh = w & 1, mq = w >> 1;

    int padded_total = 0;
    #pragma unroll
    for (int cc = 0; cc < C_; ++cc) padded_total += (ccnt[cc] + 127) & ~127;
    int nt_total = padded_total >> 7;
    if (nt_total == 0) return;
    int nchunk = GEMM_BLKS / nt_total;
    if (nchunk > MT_) nchunk = MT_;
    if (nchunk < 1) nchunk = 1;
    if (bid >= nt_total * nchunk) return;
    int panel = bid % nt_total;
    int chunk = bid / nt_total;
    int slot0 = panel << 7;

    // stage A panel: 64 KB linear from compact buffer
    {
        const __hip_bfloat16* src = A16c + ((size_t)slot0 << 8) + w * 4096 + lane * 8;
        __hip_bfloat16* dst = &As[w * 4096];
        #pragma unroll
        for (int i = 0; i < 8; ++i)
            __builtin_amdgcn_global_load_lds((const AS1 unsigned int*)(src + i * 512),
                                             (AS3 unsigned int*)(dst + i * 512), 16, 0, 0);
    }
    __syncthreads();

    int colL = lane & 15, rgrp = (lane >> 4) * 4;
    int p = 0;
    for (int mt = chunk; mt < MT_; mt += nchunk, p ^= 1) {
        floatx4 acc[4][4];
        #pragma unroll
        for (int i = 0; i < 4; ++i)
            #pragma unroll
            for (int j2 = 0; j2 < 4; ++j2) acc[i][j2] = (floatx4){0.f, 0.f, 0.f, 0.f};

        const bf16x8* Bp = (const bf16x8*)B16 + ((size_t)(mt * 16 + mq * 4) * 8) * 64 + lane;

        #pragma unroll
        for (int kt = 0; kt < 8; ++kt) {
            bf16x8 af[4], bfr[4];
            #pragma unroll
            for (int ni = 0; ni < 4; ++ni)
                af[ni] = *(const bf16x8*)&As[((nh * 4 + ni) * 8 + kt) * 512 + lane * 8];
            #pragma unroll
            for (int mi = 0; mi < 4; ++mi)
                bfr[mi] = Bp[(size_t)(mi * 8 + kt) * 64];
            __builtin_amdgcn_s_setprio(1);
            #pragma unroll
            for (int ni = 0; ni < 4; ++ni)
                #pragma unroll
                for (int mi = 0; mi < 4; ++mi)
                    acc[ni][mi] = __builtin_amdgcn_mfma_f32_16x16x32_bf16(af[ni], bfr[mi], acc[ni][mi], 0, 0, 0);
            __builtin_amdgcn_s_setprio(0);
        }

        float racc[4][4];
        #pragma unroll
        for (int ni = 0; ni < 4; ++ni)
            #pragma unroll
            for (int r = 0; r < 4; ++r) racc[ni][r] = 0.f;
        #pragma unroll
        for (int ni = 0; ni < 4; ++ni)
            #pragma unroll
            for (int mi = 0; mi < 4; ++mi)
                #pragma unroll
                for (int r = 0; r < 4; ++r)
                    racc[ni][r] += __expf(2.0f * acc[ni][mi][r]);

        #pragma unroll
        for (int ni = 0; ni < 4; ++ni)
            #pragma unroll
            for (int r = 0; r < 4; ++r) {
                float s = racc[ni][r];
                s += __shfl_xor(s, 1, 64);
                s += __shfl_xor(s, 2, 64);
                s += __shfl_xor(s, 4, 64);
                s += __shfl_xor(s, 8, 64);
                if (colL == 0) totals_s[p][mq][nh * 64 + ni * 16 + rgrp + r] = s;
            }
        // lgkm-only barrier: LDS writes visible, global (B) loads stay in flight
        asm volatile("s_waitcnt lgkmcnt(0)\n\ts_barrier" ::: "memory");
        if (t < 128)
            totpart[(size_t)mt * NP_ + slot0 + t] =
                totals_s[p][0][t] + totals_s[p][1][t] + totals_s[p][2][t] + totals_s[p][3][t];
    }
}

// ---------------- kernel 3: pass-2 own-class recompute + terms + final ----------------
__global__ __launch_bounds__(512) void k_pass2(const __hip_bfloat16* __restrict__ A16c,
                                               const __hip_bfloat16* __restrict__ B16,
                                               const int* __restrict__ ccnt,
                                               const int* __restrict__ pix,
                                               const float* __restrict__ totpart,
                                               const int* __restrict__ wmem,
                                               float* __restrict__ class_sum,
                                               int* __restrict__ done,
                                               float* __restrict__ out) {
    __shared__ __hip_bfloat16 As[64 * 256];   // 32 KB, fragment order
    __shared__ float tot_s[64];
    __shared__ int wm_s[64];
    __shared__ float bsum_s[8][64];
    __shared__ float wsum_s[8][64];
    __shared__ float down_s[64];
    __shared__ float term_s[64];

    int c = blockIdx.x, tile = blockIdx.y;
    int cnt = ccnt[c];
    int t = threadIdx.x, ws = t >> 6, lane = t & 63;

    if (tile * 64 >= cnt) {                    // empty tile: still hit the counter
        if (t == 0) {
            __threadfence();
            int old = atomicAdd(done, 1);
            if (old == P2_BLOCKS - 1) {
                float loss = 0.f, kc = 0.f;
                for (int cc = 0; cc < C_; ++cc) {
                    int cn = ccnt[cc];
                    float sc = atomicAdd(&class_sum[cc], 0.f);
                    if (cn > 0) { loss += sc / ((float)cn * (float)S_); kc += 1.f; }
                }
                out[0] = loss / fmaxf(kc, 1.f);
            }
        }
        return;
    }

    // compact-slot base (padded prefix) of this tile
    int pre = 0;
    #pragma unroll
    for (int cc = 0; cc < C_; ++cc) if (cc < c) pre += (ccnt[cc] + 127) & ~127;
    int slot0 = pre + tile * 64;

    // stage A tile: 32 KB linear from compact buffer (issued first, overlaps
    // the scattered wmem/totpart reads below)
    {
        const __hip_bfloat16* src = A16c + ((size_t)slot0 << 8) + t * 8;
        __hip_bfloat16* dst = &As[t * 8];
        #pragma unroll
        for (int i = 0; i < 4; ++i)
            __builtin_amdgcn_global_load_lds((const AS1 unsigned int*)(src + i * 4096),
                                             (AS3 unsigned int*)(dst + i * 4096), 16, 0, 0);
    }

    if (t < 64) {
        int i = tile * 64 + t;
        int p = pix[c * N_ + (i < cnt ? i : 0)];
        wm_s[t] = wmem[p];
    }

    // inline total: 8 threads per pixel sum the 38 partial slots (slot-contiguous)
    {
        int px = t >> 3, g = t & 7;
        float s = 0.f;
        for (int i = g; i < MT_; i += 8) s += totpart[(size_t)i * NP_ + slot0 + px];
        s += __shfl_xor(s, 1, 64);
        s += __shfl_xor(s, 2, 64);
        s += __shfl_xor(s, 4, 64);
        if (g == 0) tot_s[px] = s;
    }
    __syncthreads();

    floatx4 acc[4][4];
    #pragma unroll
    for (int i = 0; i < 4; ++i)
        #pragma unroll
        for (int j = 0; j < 4; ++j) acc[i][j] = (floatx4){0.f, 0.f, 0.f, 0.f};

    const bf16x8* Bp = (const bf16x8*)B16 + ((size_t)(c * 32 + ws * 4) * 8) * 64 + lane;
    #pragma unroll
    for (int kt = 0; kt < 8; ++kt) {
        bf16x8 af[4], bfr[4];
        #pragma unroll
        for (int ni = 0; ni < 4; ++ni)
            af[ni] = *(const bf16x8*)&As[(ni * 8 + kt) * 512 + lane * 8];
        #pragma unroll
        for (int mi = 0; mi < 4; ++mi) bfr[mi] = Bp[(size_t)(mi * 8 + kt) * 64];
        #pragma unroll
        for (int ni = 0; ni < 4; ++ni)
            #pragma unroll
            for (int mi = 0; mi < 4; ++mi)
                acc[ni][mi] = __builtin_amdgcn_mfma_f32_16x16x32_bf16(af[ni], bfr[mi], acc[ni][mi], 0, 0, 0);
    }

    int colL = lane & 15, rgrp = (lane >> 4) * 4;
    float Ev[4][4][4];
    #pragma unroll
    for (int ni = 0; ni < 4; ++ni)
        #pragma unroll
        for (int mi = 0; mi < 4; ++mi)
            #pragma unroll
            for (int r = 0; r < 4; ++r)
                Ev[ni][mi][r] = __expf(2.0f * acc[ni][mi][r]);

    #pragma unroll
    for (int ni = 0; ni < 4; ++ni)
        #pragma unroll
        for (int r = 0; r < 4; ++r) {
            float s = Ev[ni][0][r] + Ev[ni][1][r] + Ev[ni][2][r] + Ev[ni][3][r];
            s += __shfl_xor(s, 1, 64);
            s += __shfl_xor(s, 2, 64);
            s += __shfl_xor(s, 4, 64);
            s += __shfl_xor(s, 8, 64);
            if (colL == 0) bsum_s[ws][ni * 16 + rgrp + r] = s;
        }
    __syncthreads();
    if (t < 64) {
        float bs = 0.f;
        #pragma unroll
        for (int w2 = 0; w2 < 8; ++w2) bs += bsum_s[w2][t];
        down_s[t] = tot_s[t] - bs;
    }
    __syncthreads();

    #pragma unroll
    for (int ni = 0; ni < 4; ++ni)
        #pragma unroll
        for (int r = 0; r < 4; ++r) {
            int row = ni * 16 + rgrp + r;
            bool sel = (wm_s[row] == 1) ? (ws < 4) : (ws >= 4);
            float tt = 0.f;
            if (sel) {
                float dwn = down_s[row];
                #pragma unroll
                for (int mi = 0; mi < 4; ++mi) {
                    float pv = Ev[ni][mi][r];
                    tt += -logf(pv / (pv + dwn + 1e-12f) + 1e-12f);
                }
            }
            tt += __shfl_xor(tt, 1, 64);
            tt += __shfl_xor(tt, 2, 64);
            tt += __shfl_xor(tt, 4, 64);
            tt += __shfl_xor(tt, 8, 64);
            if (colL == 0) wsum_s[ws][row] = tt;
        }
    __syncthreads();
    if (t < 64) {
        int i = tile * 64 + t;
        float s = 0.f;
        if (i < cnt) {
            #pragma unroll
            for (int w2 = 0; w2 < 8; ++w2) s += wsum_s[w2][t];
        }
        term_s[t] = s;
    }
    __syncthreads();
    if (t < 64) {
        float s = term_s[t];
        #pragma unroll
        for (int off = 1; off < 64; off <<= 1) s += __shfl_xor(s, off, 64);
        if (t == 0) {
            atomicAdd(&class_sum[c], s);
            __threadfence();
            int old = atomicAdd(done, 1);
            if (old == P2_BLOCKS - 1) {
                float loss = 0.f, kc = 0.f;
                for (int cc = 0; cc < C_; ++cc) {
                    int cn = ccnt[cc];
                    float sc = atomicAdd(&class_sum[cc], 0.f);
                    if (cn > 0) { loss += sc / ((float)cn * (float)S_); kc += 1.f; }
                }
                out[0] = loss / fmaxf(kc, 1.f);
            }
        }
    }
}

extern "C" void kernel_launch(void* const* d_in, const int* in_sizes, int n_in,
                              void* d_out, int out_size, void* d_ws, size_t ws_size,
                              hipStream_t stream) {
    const float* mem    = (const float*)d_in[0];
    const float* pred   = (const float*)d_in[1];
    const int*   labels = (const int*)  d_in[2];
    const int*   mask   = (const int*)  d_in[3];
    const int*   wmem   = (const int*)  d_in[4];
    float* out = (float*)d_out;

    float* ws = (float*)d_ws;
    float* totpart   = ws;                            // 38*NP_ = 715,008 floats
    int*   ctrl      = (int*)(ws + 715008);           // 40 words
    int*   ccnt      = ctrl;                          // 19
    float* class_sum = (float*)(ctrl + 19);           // 19
    int*   done      = ctrl + 38;                     // 1
    int*   pix       = (int*)(ws + 715048);           // 19*N_ = 311,296 ints
    int*   slotmap   = (int*)(ws + 1026344);          // N_ = 16,384 ints
    __hip_bfloat16* A16c = (__hip_bfloat16*)(ws + 1042728);   // NP_*256 bf16 (compact)
    __hip_bfloat16* B16  = (__hip_bfloat16*)(ws + 3451176);   // M_*256 bf16 (frag order)

    hipMemsetAsync(ctrl, 0, 40 * sizeof(int), stream);

    k_bucket<<<N_ / 256, 256, 0, stream>>>(labels, mask, ccnt, pix, slotmap);

    k_prep<<<PREP_TOTAL, 256, 0, stream>>>(pred, mem, A16c, B16, ccnt, slotmap);

    k_pass1<<<GEMM_BLKS, 512, 0, stream>>>(A16c, B16, ccnt, totpart);

    dim3 g2(C_, 16);
    k_pass2<<<g2, 512, 0, stream>>>(A16c, B16, ccnt, pix, totpart, wmem,
                                    class_sum, done, out);
}

// Round 9
// 169.778 us; speedup vs baseline: 1.3190x; 1.0125x over previous
//
#include <hip/hip_runtime.h>
#include <hip/hip_bf16.h>
#include <math.h>

#define B_ 4
#define F_ 256
#define C_ 19
#define S_ 256
#define N_ 16384
#define M_ 9728
#define MT_ 38           // m-tiles (256 cols each) in pass1
#define NP_ 18816        // totpart slot capacity (>= any padded_total)
#define PREP_PRED 256
#define PREP_TOTAL 2688  // 256 pred + 2432 mem
#define GEMM_BLKS 512
#define P2_BLOCKS (C_ * 16)

typedef __bf16 bf16_t;
typedef bf16_t bf16x8 __attribute__((ext_vector_type(8)));
typedef float floatx4 __attribute__((ext_vector_type(4)));

#define AS1 __attribute__((address_space(1)))
#define AS3 __attribute__((address_space(3)))

// Fragment-order layout: element (row, f) lives at
//   ((row>>4)*8 + (f>>5))*512 + ((f>>3)&3)*128 + (row&15)*8 + (f&7)
// For 64-aligned panels this equals panel_base*256 + 8*k with k the linear
// 16B-chunk index -> global_load_lds can stage panels linearly.
__device__ inline size_t fragoff(int row, int f) {
    return ((size_t)((row >> 4) * 8 + (f >> 5))) * 512
         + (size_t)((((f >> 3) & 3) * 128) + ((row & 15) * 8) + (f & 7));
}

// ---------------- kernel 0: bucketing + inverse slot map ----------
// ctrl zeroed by hipMemsetAsync before this kernel.
__global__ __launch_bounds__(256) void k_bucket(const int* __restrict__ labels,
                                                const int* __restrict__ mask,
                                                int* __restrict__ ccnt,
                                                int* __restrict__ pix,
                                                int* __restrict__ slotmap) {
    __shared__ int hist[C_], base_s[C_], cur[C_];
    int t = threadIdx.x;
    int n0 = blockIdx.x * 256;
    if (t < C_) { hist[t] = 0; cur[t] = 0; }
    __syncthreads();
    int myc = labels[n0 + t];
    int mym = mask[n0 + t];
    if (mym) atomicAdd(&hist[myc], 1);
    __syncthreads();
    if (t < C_) base_s[t] = atomicAdd(&ccnt[t], hist[t]);
    __syncthreads();
    int sm = -1;
    if (mym) {
        int o = atomicAdd(&cur[myc], 1);
        int pos = base_s[myc] + o;
        pix[myc * N_ + pos] = n0 + t;
        sm = (myc << 16) | pos;
    }
    slotmap[n0 + t] = sm;
}

// ---------------- kernel 1: prep -> compact A16c (masked only, 64-padded) + B16 ----------
__global__ __launch_bounds__(256) void k_prep(const float* __restrict__ pred,
                                              const float* __restrict__ mem,
                                              __hip_bfloat16* __restrict__ A16c,
                                              __hip_bfloat16* __restrict__ B16,
                                              const int* __restrict__ ccnt,
                                              const int* __restrict__ slotmap) {
    int bid = blockIdx.x;
    int t = threadIdx.x;
    if (bid < PREP_PRED) {
        __shared__ float part[4][64];
        __shared__ float invf_s[64];
        __shared__ int pre_s[C_];
        int b = bid >> 6, hw0 = (bid & 63) * 64;
        int j = t & 63, q = t >> 6;
        int n0 = b * 4096 + hw0;

        if (t < C_) {                       // 64-padded class prefix (ccnt final)
            int pre = 0;
            for (int cc = 0; cc < t; ++cc) pre += (ccnt[cc] + 63) & ~63;
            pre_s[t] = pre;
        }

        const float* base = pred + ((size_t)b * F_ + q * 64) * 4096 + hw0 + j;
        float v[64];
        float s = 0.f;
        #pragma unroll
        for (int i = 0; i < 64; ++i) {
            float x = base[(size_t)i * 4096];
            v[i] = x;
            s += x * x;
        }
        part[q][j] = s;
        __syncthreads();
        if (t < 64) invf_s[t] = 1.0f / sqrtf(part[0][t] + part[1][t] + part[2][t] + part[3][t]);
        __syncthreads();
        int sm = slotmap[n0 + j];
        if (sm >= 0) {
            int slot = pre_s[sm >> 16] + (sm & 0xffff);
            float invf = invf_s[j];
            #pragma unroll
            for (int c = 0; c < 8; ++c) {
                int f = q * 64 + c * 8;
                __hip_bfloat16 tmp[8];
                #pragma unroll
                for (int u = 0; u < 8; ++u) tmp[u] = __float2bfloat16(v[c * 8 + u] * invf);
                *(float4*)&A16c[fragoff(slot, f)] = *(float4*)tmp;
            }
        }
    } else {
        int row  = (bid - PREP_PRED) * 4 + (t >> 6);
        int lane = t & 63;
        float4 a = ((const float4*)(mem + (size_t)row * F_))[lane];
        float s = a.x*a.x + a.y*a.y + a.z*a.z + a.w*a.w;
        #pragma unroll
        for (int off = 32; off; off >>= 1) s += __shfl_xor(s, off, 64);
        float invm = 1.0f / sqrtf(s);
        __hip_bfloat16 tmp[4];
        tmp[0] = __float2bfloat16(a.x * invm);
        tmp[1] = __float2bfloat16(a.y * invm);
        tmp[2] = __float2bfloat16(a.z * invm);
        tmp[3] = __float2bfloat16(a.w * invm);
        *(float2*)&B16[fragoff(row, lane * 4)] = *(float2*)tmp;
    }
}

// ---------------- kernel 2: pass-1 GEMM over compact slots ----------
// nt_total = ceil(padded_total/128) panels (last panel may include garbage
// rows: their totpart slots are never read). nchunk = min(512/nt_total, 38).
// Balanced contiguous mt ranges: chunk covers [chunk*38/nchunk,(chunk+1)*38/nchunk).
// A panel staged linearly via global_load_lds (8 waves of 64x64, acc[4][4]);
// lgkm-only combine barrier per mt.
__global__ __launch_bounds__(512, 4) void k_pass1(const __hip_bfloat16* __restrict__ A16c,
                                                  const __hip_bfloat16* __restrict__ B16,
                                                  const int* __restrict__ ccnt,
                                                  float* __restrict__ totpart) {
    __shared__ __hip_bfloat16 As[128 * 256];     // 64 KB
    __shared__ float totals_s[2][4][128];        // 4 KB (double-buffered)
    int bid = blockIdx.x;
    int t = threadIdx.x;
    int w = t >> 6, lane = t & 63;
    int nh = w & 1, mq = w >> 1;

    int padded_total = 0;
    #pragma unroll
    for (int cc = 0; cc < C_; ++cc) padded_total += (ccnt[cc] + 63) & ~63;
    int nt_total = (padded_total + 127) >> 7;
    if (nt_total == 0) return;
    int nchunk = GEMM_BLKS / nt_total;
    if (nchunk > MT_) nchunk = MT_;
    if (nchunk < 1) nchunk = 1;
    if (bid >= nt_total * nchunk) return;
    int panel = bid % nt_total;
    int chunk = bid / nt_total;
    int slot0 = panel << 7;
    int mt_lo = (chunk * MT_) / nchunk;
    int mt_hi = ((chunk + 1) * MT_) / nchunk;

    // stage A panel: 64 KB linear from compact buffer
    {
        const __hip_bfloat16* src = A16c + ((size_t)slot0 << 8) + w * 4096 + lane * 8;
        __hip_bfloat16* dst = &As[w * 4096];
        #pragma unroll
        for (int i = 0; i < 8; ++i)
            __builtin_amdgcn_global_load_lds((const AS1 unsigned int*)(src + i * 512),
                                             (AS3 unsigned int*)(dst + i * 512), 16, 0, 0);
    }
    __syncthreads();

    int colL = lane & 15, rgrp = (lane >> 4) * 4;
    int p = 0;
    for (int mt = mt_lo; mt < mt_hi; ++mt, p ^= 1) {
        floatx4 acc[4][4];
        #pragma unroll
        for (int i = 0; i < 4; ++i)
            #pragma unroll
            for (int j2 = 0; j2 < 4; ++j2) acc[i][j2] = (floatx4){0.f, 0.f, 0.f, 0.f};

        const bf16x8* Bp = (const bf16x8*)B16 + ((size_t)(mt * 16 + mq * 4) * 8) * 64 + lane;

        #pragma unroll
        for (int kt = 0; kt < 8; ++kt) {
            bf16x8 af[4], bfr[4];
            #pragma unroll
            for (int ni = 0; ni < 4; ++ni)
                af[ni] = *(const bf16x8*)&As[((nh * 4 + ni) * 8 + kt) * 512 + lane * 8];
            #pragma unroll
            for (int mi = 0; mi < 4; ++mi)
                bfr[mi] = Bp[(size_t)(mi * 8 + kt) * 64];
            __builtin_amdgcn_s_setprio(1);
            #pragma unroll
            for (int ni = 0; ni < 4; ++ni)
                #pragma unroll
                for (int mi = 0; mi < 4; ++mi)
                    acc[ni][mi] = __builtin_amdgcn_mfma_f32_16x16x32_bf16(af[ni], bfr[mi], acc[ni][mi], 0, 0, 0);
            __builtin_amdgcn_s_setprio(0);
        }

        float racc[4][4];
        #pragma unroll
        for (int ni = 0; ni < 4; ++ni)
            #pragma unroll
            for (int r = 0; r < 4; ++r) racc[ni][r] = 0.f;
        #pragma unroll
        for (int ni = 0; ni < 4; ++ni)
            #pragma unroll
            for (int mi = 0; mi < 4; ++mi)
                #pragma unroll
                for (int r = 0; r < 4; ++r)
                    racc[ni][r] += __expf(2.0f * acc[ni][mi][r]);

        #pragma unroll
        for (int ni = 0; ni < 4; ++ni)
            #pragma unroll
            for (int r = 0; r < 4; ++r) {
                float s = racc[ni][r];
                s += __shfl_xor(s, 1, 64);
                s += __shfl_xor(s, 2, 64);
                s += __shfl_xor(s, 4, 64);
                s += __shfl_xor(s, 8, 64);
                if (colL == 0) totals_s[p][mq][nh * 64 + ni * 16 + rgrp + r] = s;
            }
        // lgkm-only barrier: LDS writes visible, global (B) loads stay in flight
        asm volatile("s_waitcnt lgkmcnt(0)\n\ts_barrier" ::: "memory");
        if (t < 128)
            totpart[(size_t)mt * NP_ + slot0 + t] =
                totals_s[p][0][t] + totals_s[p][1][t] + totals_s[p][2][t] + totals_s[p][3][t];
    }
}

// ---------------- kernel 3: pass-2 own-class recompute + terms + final ----------------
__global__ __launch_bounds__(512) void k_pass2(const __hip_bfloat16* __restrict__ A16c,
                                               const __hip_bfloat16* __restrict__ B16,
                                               const int* __restrict__ ccnt,
                                               const int* __restrict__ pix,
                                               const float* __restrict__ totpart,
                                               const int* __restrict__ wmem,
                                               float* __restrict__ class_sum,
                                               int* __restrict__ done,
                                               float* __restrict__ out) {
    __shared__ __hip_bfloat16 As[64 * 256];   // 32 KB, fragment order
    __shared__ float tot_s[64];
    __shared__ int wm_s[64];
    __shared__ float bsum_s[8][64];
    __shared__ float wsum_s[8][64];
    __shared__ float down_s[64];
    __shared__ float term_s[64];

    int c = blockIdx.x, tile = blockIdx.y;
    int cnt = ccnt[c];
    int t = threadIdx.x, ws = t >> 6, lane = t & 63;

    if (tile * 64 >= cnt) {                    // empty tile: still hit the counter
        if (t == 0) {
            __threadfence();
            int old = atomicAdd(done, 1);
            if (old == P2_BLOCKS - 1) {
                float loss = 0.f, kc = 0.f;
                for (int cc = 0; cc < C_; ++cc) {
                    int cn = ccnt[cc];
                    float sc = atomicAdd(&class_sum[cc], 0.f);
                    if (cn > 0) { loss += sc / ((float)cn * (float)S_); kc += 1.f; }
                }
                out[0] = loss / fmaxf(kc, 1.f);
            }
        }
        return;
    }

    // compact-slot base (64-padded prefix) of this tile
    int pre = 0;
    #pragma unroll
    for (int cc = 0; cc < C_; ++cc) if (cc < c) pre += (ccnt[cc] + 63) & ~63;
    int slot0 = pre + tile * 64;

    // stage A tile: 32 KB linear from compact buffer (issued first, overlaps
    // the scattered wmem/totpart reads below)
    {
        const __hip_bfloat16* src = A16c + ((size_t)slot0 << 8) + t * 8;
        __hip_bfloat16* dst = &As[t * 8];
        #pragma unroll
        for (int i = 0; i < 4; ++i)
            __builtin_amdgcn_global_load_lds((const AS1 unsigned int*)(src + i * 4096),
                                             (AS3 unsigned int*)(dst + i * 4096), 16, 0, 0);
    }

    if (t < 64) {
        int i = tile * 64 + t;
        int p = pix[c * N_ + (i < cnt ? i : 0)];
        wm_s[t] = wmem[p];
    }

    // inline total: 8 threads per pixel sum the 38 partial slots (slot-contiguous)
    {
        int px = t >> 3, g = t & 7;
        float s = 0.f;
        for (int i = g; i < MT_; i += 8) s += totpart[(size_t)i * NP_ + slot0 + px];
        s += __shfl_xor(s, 1, 64);
        s += __shfl_xor(s, 2, 64);
        s += __shfl_xor(s, 4, 64);
        if (g == 0) tot_s[px] = s;
    }
    __syncthreads();

    floatx4 acc[4][4];
    #pragma unroll
    for (int i = 0; i < 4; ++i)
        #pragma unroll
        for (int j = 0; j < 4; ++j) acc[i][j] = (floatx4){0.f, 0.f, 0.f, 0.f};

    const bf16x8* Bp = (const bf16x8*)B16 + ((size_t)(c * 32 + ws * 4) * 8) * 64 + lane;
    #pragma unroll
    for (int kt = 0; kt < 8; ++kt) {
        bf16x8 af[4], bfr[4];
        #pragma unroll
        for (int ni = 0; ni < 4; ++ni)
            af[ni] = *(const bf16x8*)&As[(ni * 8 + kt) * 512 + lane * 8];
        #pragma unroll
        for (int mi = 0; mi < 4; ++mi) bfr[mi] = Bp[(size_t)(mi * 8 + kt) * 64];
        #pragma unroll
        for (int ni = 0; ni < 4; ++ni)
            #pragma unroll
            for (int mi = 0; mi < 4; ++mi)
                acc[ni][mi] = __builtin_amdgcn_mfma_f32_16x16x32_bf16(af[ni], bfr[mi], acc[ni][mi], 0, 0, 0);
    }

    int colL = lane & 15, rgrp = (lane >> 4) * 4;
    float Ev[4][4][4];
    #pragma unroll
    for (int ni = 0; ni < 4; ++ni)
        #pragma unroll
        for (int mi = 0; mi < 4; ++mi)
            #pragma unroll
            for (int r = 0; r < 4; ++r)
                Ev[ni][mi][r] = __expf(2.0f * acc[ni][mi][r]);

    #pragma unroll
    for (int ni = 0; ni < 4; ++ni)
        #pragma unroll
        for (int r = 0; r < 4; ++r) {
            float s = Ev[ni][0][r] + Ev[ni][1][r] + Ev[ni][2][r] + Ev[ni][3][r];
            s += __shfl_xor(s, 1, 64);
            s += __shfl_xor(s, 2, 64);
            s += __shfl_xor(s, 4, 64);
            s += __shfl_xor(s, 8, 64);
            if (colL == 0) bsum_s[ws][ni * 16 + rgrp + r] = s;
        }
    __syncthreads();
    if (t < 64) {
        float bs = 0.f;
        #pragma unroll
        for (int w2 = 0; w2 < 8; ++w2) bs += bsum_s[w2][t];
        down_s[t] = tot_s[t] - bs;
    }
    __syncthreads();

    #pragma unroll
    for (int ni = 0; ni < 4; ++ni)
        #pragma unroll
        for (int r = 0; r < 4; ++r) {
            int row = ni * 16 + rgrp + r;
            bool sel = (wm_s[row] == 1) ? (ws < 4) : (ws >= 4);
            float tt = 0.f;
            if (sel) {
                float dwn = down_s[row];
                // sum_mi -log(x_mi) == -log(prod_mi x_mi); x >= 1.9e-6 so the
                // 4-way product >= 1.3e-23 stays normal. eps-shift error ~1e-8
                // relative, far under bf16 GEMM noise.
                float prod = 1.f;
                #pragma unroll
                for (int mi = 0; mi < 4; ++mi) {
                    float pv = Ev[ni][mi][r];
                    prod *= pv / (pv + dwn + 1e-12f);
                }
                tt = -logf(prod);
            }
            tt += __shfl_xor(tt, 1, 64);
            tt += __shfl_xor(tt, 2, 64);
            tt += __shfl_xor(tt, 4, 64);
            tt += __shfl_xor(tt, 8, 64);
            if (colL == 0) wsum_s[ws][row] = tt;
        }
    __syncthreads();
    if (t < 64) {
        int i = tile * 64 + t;
        float s = 0.f;
        if (i < cnt) {
            #pragma unroll
            for (int w2 = 0; w2 < 8; ++w2) s += wsum_s[w2][t];
        }
        term_s[t] = s;
    }
    __syncthreads();
    if (t < 64) {
        float s = term_s[t];
        #pragma unroll
        for (int off = 1; off < 64; off <<= 1) s += __shfl_xor(s, off, 64);
        if (t == 0) {
            atomicAdd(&class_sum[c], s);
            __threadfence();
            int old = atomicAdd(done, 1);
            if (old == P2_BLOCKS - 1) {
                float loss = 0.f, kc = 0.f;
                for (int cc = 0; cc < C_; ++cc) {
                    int cn = ccnt[cc];
                    float sc = atomicAdd(&class_sum[cc], 0.f);
                    if (cn > 0) { loss += sc / ((float)cn * (float)S_); kc += 1.f; }
                }
                out[0] = loss / fmaxf(kc, 1.f);
            }
        }
    }
}

extern "C" void kernel_launch(void* const* d_in, const int* in_sizes, int n_in,
                              void* d_out, int out_size, void* d_ws, size_t ws_size,
                              hipStream_t stream) {
    const float* mem    = (const float*)d_in[0];
    const float* pred   = (const float*)d_in[1];
    const int*   labels = (const int*)  d_in[2];
    const int*   mask   = (const int*)  d_in[3];
    const int*   wmem   = (const int*)  d_in[4];
    float* out = (float*)d_out;

    float* ws = (float*)d_ws;
    float* totpart   = ws;                            // 38*NP_ = 715,008 floats
    int*   ctrl      = (int*)(ws + 715008);           // 40 words
    int*   ccnt      = ctrl;                          // 19
    float* class_sum = (float*)(ctrl + 19);           // 19
    int*   done      = ctrl + 38;                     // 1
    int*   pix       = (int*)(ws + 715048);           // 19*N_ = 311,296 ints
    int*   slotmap   = (int*)(ws + 1026344);          // N_ = 16,384 ints
    __hip_bfloat16* A16c = (__hip_bfloat16*)(ws + 1042728);   // NP_*256 bf16 (compact)
    __hip_bfloat16* B16  = (__hip_bfloat16*)(ws + 3451176);   // M_*256 bf16 (frag order)

    hipMemsetAsync(ctrl, 0, 40 * sizeof(int), stream);

    k_bucket<<<N_ / 256, 256, 0, stream>>>(labels, mask, ccnt, pix, slotmap);

    k_prep<<<PREP_TOTAL, 256, 0, stream>>>(pred, mem, A16c, B16, ccnt, slotmap);

    k_pass1<<<GEMM_BLKS, 512, 0, stream>>>(A16c, B16, ccnt, totpart);

    dim3 g2(C_, 16);
    k_pass2<<<g2, 512, 0, stream>>>(A16c, B16, ccnt, pix, totpart, wmem,
                                    class_sum, done, out);
}